// Round 2
// baseline (624.290 us; speedup 1.0000x reference)
//
#include <hip/hip_runtime.h>
#include <hip/hip_bf16.h>

#define PP 32000
#define DD 128
#define BBATCH 4096

typedef __bf16 bf16x8 __attribute__((ext_vector_type(8)));
typedef float f32x4 __attribute__((ext_vector_type(4)));
typedef unsigned short ushort8 __attribute__((ext_vector_type(8)));

// RNE float -> bf16 (inputs are finite; no NaN handling needed)
__device__ __forceinline__ unsigned short f2bf(float f) {
    unsigned u = __float_as_uint(f);
    u += 0x7FFFu + ((u >> 16) & 1u);
    return (unsigned short)(u >> 16);
}

// ---------------------------------------------------------------------------
// Fragment-major operand layout:
// For mfma_f32_16x16x32_bf16, lane l of a wave needs
//   A[m = l&15][k = (l>>4)*8 + j]  (j = 0..7, one bf16x8 = 16 B)
// We store both operands pre-tiled as  [row16][ks][lane][8]  so a wave's
// fragment load is  base + lane*16B  -> ONE coalesced 1024 B instruction
// (8 full 128B lines) instead of 16 scattered 64 B half-lines.
// flat elem index: ((row16*4 + ks)*64 + l)*8 + j
//   with row = row16*16 + (l&15),  k = ks*32 + (l>>4)*8 + j
// ---------------------------------------------------------------------------

// Hb_tiled[b16][ks][l][j] = bf16(relu(W[k][x[b,0]] + W[k][x[b,1]]))
// One element per thread (max TLP for the strided W gather; W is LLC-hot).
// Writes are 2B scattered within 1KB subtiles -> merged in L2, 1 MB total.
__global__ void prep_hidden_kernel(const int* __restrict__ x,
                                   const float* __restrict__ W,
                                   unsigned short* __restrict__ Hb) {
    const int b = (blockIdx.x << 1) + (threadIdx.x >> 7);
    const int d = threadIdx.x & 127;
    const int i0 = x[2 * b];
    const int i1 = x[2 * b + 1];
    float h = W[(size_t)d * PP + i0] + W[(size_t)d * PP + i1];
    h = h > 0.0f ? h : 0.0f;
    const int st = ((b >> 4) << 2) | (d >> 5);             // b16*4 + ks
    const int l  = (((d & 31) >> 3) << 4) | (b & 15);      // lane
    Hb[(st << 9) + (l << 3) + (d & 7)] = f2bf(h);
}

// Vb_tiled: thread t produces exactly the 16 B chunk [t] of the tiled buffer
// (fully coalesced writes); reads two float4 from V[p][k0..k0+8].
__global__ void prep_v_kernel(const float* __restrict__ V,
                              unsigned short* __restrict__ Vb) {
    const int t  = blockIdx.x * 256 + threadIdx.x;   // 512000 chunks
    const int l  = t & 63;
    const int st = t >> 6;
    const int ks  = st & 3;
    const int p16 = st >> 2;
    const int p  = (p16 << 4) | (l & 15);
    const int k0 = (ks << 5) | ((l >> 4) << 3);
    const float4 v0 = *reinterpret_cast<const float4*>(V + (size_t)p * DD + k0);
    const float4 v1 = *reinterpret_cast<const float4*>(V + (size_t)p * DD + k0 + 4);
    ushort8 o;
    o[0] = f2bf(v0.x); o[1] = f2bf(v0.y); o[2] = f2bf(v0.z); o[3] = f2bf(v0.w);
    o[4] = f2bf(v1.x); o[5] = f2bf(v1.y); o[6] = f2bf(v1.z); o[7] = f2bf(v1.w);
    *reinterpret_cast<ushort8*>(Vb + (size_t)t * 8) = o;
}

// out[b][p] = sum_k Hb[b][k] * Vb[p][k]
// MFMA roles: M = p (A from Vb), N = b (B from Hb), K = d.
// Per wave: 64x64 output tile, 4x4 subtiles of 16x16, K=128 in 4 ks of 32.
// All operand loads are coalesced 1024B (fragment-major layout above).
// C/D layout: D[m=(lane>>4)*4+reg][n=lane&15] (verified m89/m91) ->
//   reg axis = 4 consecutive p at fixed b -> f32x4 store along output row.
__global__ void gemm_kernel(const unsigned short* __restrict__ Vb,
                            const unsigned short* __restrict__ Hb,
                            float* __restrict__ out) {
    // bijective XCD swizzle (8000 blocks % 8 XCDs == 0): each XCD gets a
    // contiguous 1000-block slice -> its own 1MB Vb slice + 1MB Hb L2-resident.
    const int bid = (blockIdx.x & 7) * 1000 + (blockIdx.x >> 3);
    const int wid  = (bid << 2) + (threadIdx.x >> 6);
    const int lane = threadIdx.x & 63;
    const int bt = wid & 63;   // 64 b-tiles of 64 (fast: block's 4 waves share pt)
    const int pt = wid >> 6;   // 500 p-tiles of 64
    const int col = lane & 15;
    const int kq  = lane >> 4;

    const int p0 = pt << 6;
    const int b0 = bt << 6;

    // chunk index = (row16*4 + ks)*64 + lane ; row16 = pt*4 + i (resp bt*4 + j)
    const bf16x8* Abase = reinterpret_cast<const bf16x8*>(Vb) + ((pt << 4) << 6) + lane;
    const bf16x8* Bbase = reinterpret_cast<const bf16x8*>(Hb) + ((bt << 4) << 6) + lane;

    f32x4 acc[4][4];
    const f32x4 zero = {0.0f, 0.0f, 0.0f, 0.0f};
    #pragma unroll
    for (int i = 0; i < 4; ++i)
        #pragma unroll
        for (int j = 0; j < 4; ++j)
            acc[i][j] = zero;

    #pragma unroll
    for (int ks = 0; ks < 4; ++ks) {
        bf16x8 a[4], bb[4];
        #pragma unroll
        for (int i = 0; i < 4; ++i)
            a[i] = Abase[((i << 2) + ks) << 6];
        #pragma unroll
        for (int j = 0; j < 4; ++j)
            bb[j] = Bbase[((j << 2) + ks) << 6];
        #pragma unroll
        for (int i = 0; i < 4; ++i)
            #pragma unroll
            for (int j = 0; j < 4; ++j)
                acc[i][j] = __builtin_amdgcn_mfma_f32_16x16x32_bf16(
                    a[i], bb[j], acc[i][j], 0, 0, 0);
    }

    // store: b = b0 + j*16 + col (row), p = p0 + i*16 + kq*4 + r (contiguous)
    // nontemporal: out is write-once 524MB, don't evict operands from L2.
    #pragma unroll
    for (int j = 0; j < 4; ++j) {
        float* row = out + (size_t)(b0 + (j << 4) + col) * PP + p0 + (kq << 2);
        #pragma unroll
        for (int i = 0; i < 4; ++i)
            __builtin_nontemporal_store(acc[i][j],
                reinterpret_cast<f32x4*>(row + (i << 4)));
    }
}

extern "C" void kernel_launch(void* const* d_in, const int* in_sizes, int n_in,
                              void* d_out, int out_size, void* d_ws, size_t ws_size,
                              hipStream_t stream) {
    const int*   x = (const int*)d_in[0];
    const float* W = (const float*)d_in[1];
    const float* V = (const float*)d_in[2];
    float* out = (float*)d_out;

    // workspace: Hb_tiled [4096*128] bf16 (1 MB), then Vb_tiled [32000*128] bf16 (8 MB)
    unsigned short* Hb = (unsigned short*)d_ws;
    unsigned short* Vb = Hb + (size_t)BBATCH * DD;

    prep_hidden_kernel<<<BBATCH / 2, 256, 0, stream>>>(x, W, Hb);
    prep_v_kernel<<<(PP * DD) / (8 * 256), 256, 0, stream>>>(V, Vb);
    gemm_kernel<<<8000, 256, 0, stream>>>(Vb, Hb, out);
}

// Round 4
// 556.968 us; speedup vs baseline: 1.1209x; 1.1209x over previous
//
#include <hip/hip_runtime.h>
#include <hip/hip_bf16.h>

#define PP 32000
#define DD 128
#define BBATCH 4096

typedef __bf16 bf16x8 __attribute__((ext_vector_type(8)));
typedef float f32x4 __attribute__((ext_vector_type(4)));
typedef unsigned short ushort8 __attribute__((ext_vector_type(8)));

// RNE float -> bf16 (inputs are finite; no NaN handling needed)
__device__ __forceinline__ unsigned short f2bf(float f) {
    unsigned u = __float_as_uint(f);
    u += 0x7FFFu + ((u >> 16) & 1u);
    return (unsigned short)(u >> 16);
}

// ---------------------------------------------------------------------------
// Fragment-major operand layout (verified passing, round 2):
// For mfma_f32_16x16x32_bf16, lane l needs  A[m=l&15][k=(l>>4)*8+j], j=0..7.
// Both operands pre-tiled as [row16][ks][lane][8]: a wave's fragment load is
// base + lane*16B -> ONE coalesced 1024B instruction.
// flat elem index: ((row16*4 + ks)*64 + l)*8 + j
//   with row = row16*16 + (l&15),  k = ks*32 + (l>>4)*8 + j
// ---------------------------------------------------------------------------

__global__ void prep_hidden_kernel(const int* __restrict__ x,
                                   const float* __restrict__ W,
                                   unsigned short* __restrict__ Hb) {
    const int b = (blockIdx.x << 1) + (threadIdx.x >> 7);
    const int d = threadIdx.x & 127;
    const int i0 = x[2 * b];
    const int i1 = x[2 * b + 1];
    float h = W[(size_t)d * PP + i0] + W[(size_t)d * PP + i1];
    h = h > 0.0f ? h : 0.0f;
    const int st = ((b >> 4) << 2) | (d >> 5);             // b16*4 + ks
    const int l  = (((d & 31) >> 3) << 4) | (b & 15);      // lane
    Hb[(st << 9) + (l << 3) + (d & 7)] = f2bf(h);
}

__global__ void prep_v_kernel(const float* __restrict__ V,
                              unsigned short* __restrict__ Vb) {
    const int t  = blockIdx.x * 256 + threadIdx.x;   // 512000 chunks of 16B
    const int l  = t & 63;
    const int st = t >> 6;
    const int ks  = st & 3;
    const int p16 = st >> 2;
    const int p  = (p16 << 4) | (l & 15);
    const int k0 = (ks << 5) | ((l >> 4) << 3);
    const float4 v0 = *reinterpret_cast<const float4*>(V + (size_t)p * DD + k0);
    const float4 v1 = *reinterpret_cast<const float4*>(V + (size_t)p * DD + k0 + 4);
    ushort8 o;
    o[0] = f2bf(v0.x); o[1] = f2bf(v0.y); o[2] = f2bf(v0.z); o[3] = f2bf(v0.w);
    o[4] = f2bf(v1.x); o[5] = f2bf(v1.y); o[6] = f2bf(v1.z); o[7] = f2bf(v1.w);
    *reinterpret_cast<ushort8*>(Vb + (size_t)t * 8) = o;
}

// out[b][p] = sum_k Hb[b][k] * Vb[p][k]
// Block = 4 waves, ALL at the same 64-b tile (BT), spanning 256 p (wave w owns
// p-tile PT*4+w). MFMA roles/fragment layouts unchanged (verified round 2).
// LDS-transposed epilogue: acc staged through 32KB LDS in 2 phases of 32
// b-rows; readback gives lane l the p-chunk [l*4, l*4+4) of one row, so each
// output store instruction writes 1024B CONTIGUOUS (8 full 128B lines) -- the
// same local pattern as the 6.3TB/s fill kernel -- instead of 16 rows x 64B.
// LDS slot swizzle: logical 16B slot s of row br lives at s^br (bijective,
// conflict-free at the inherent 8-phase minimum for b128 ops).
__global__ void gemm_kernel(const unsigned short* __restrict__ Vb,
                            const unsigned short* __restrict__ Hb,
                            float* __restrict__ out) {
    __shared__ f32x4 lds4[32 * 64];   // 32 rows x 64 slots x 16B = 32 KB

    // bijective XCD swizzle (8000 % 8 == 0): each XCD gets a contiguous
    // 1000-block slice -> ~16 p-tiles (1MB Vb) + full Hb (1MB) L2-resident.
    const int bid = (blockIdx.x & 7) * 1000 + (blockIdx.x >> 3);
    const int PT = bid >> 6;       // 0..124 : 256-wide p block
    const int BT = bid & 63;       // 0..63  : 64-wide b block (fast axis)
    const int w    = threadIdx.x >> 6;   // wave 0..3 -> p-subtile
    const int lane = threadIdx.x & 63;
    const int col = lane & 15;
    const int kq  = lane >> 4;

    const int pt = (PT << 2) + w;  // global 64-p tile
    const int b0 = BT << 6;
    const int P0 = PT << 8;

    const bf16x8* Abase = reinterpret_cast<const bf16x8*>(Vb) + (pt << 10) + lane;
    const bf16x8* Bbase = reinterpret_cast<const bf16x8*>(Hb) + (BT << 10) + lane;

    f32x4 acc[4][4];
    const f32x4 zero = {0.0f, 0.0f, 0.0f, 0.0f};
    #pragma unroll
    for (int i = 0; i < 4; ++i)
        #pragma unroll
        for (int j = 0; j < 4; ++j)
            acc[i][j] = zero;

    #pragma unroll
    for (int ks = 0; ks < 4; ++ks) {
        bf16x8 a[4], bb[4];
        #pragma unroll
        for (int i = 0; i < 4; ++i)
            a[i] = Abase[((i << 2) + ks) << 6];
        #pragma unroll
        for (int j = 0; j < 4; ++j)
            bb[j] = Bbase[((j << 2) + ks) << 6];
        #pragma unroll
        for (int i = 0; i < 4; ++i)
            #pragma unroll
            for (int j = 0; j < 4; ++j)
                acc[i][j] = __builtin_amdgcn_mfma_f32_16x16x32_bf16(
                    a[i], bb[j], acc[i][j], 0, 0, 0);
    }

    // -------- LDS-transposed epilogue, 2 phases of 32 b-rows --------
    // acc[i][j] lane layout (verified): value (i,j,reg r) is
    //   b = b0 + j*16 + col ,  p = pt*64 + i*16 + kq*4 + r
    // Phase ph covers j in {2ph, 2ph+1} i.e. local rows br = (j2*16+col).
    // Slot (16B) index within a 256-p row: s = w*16 + i*4 + kq (0..63).
    #pragma unroll
    for (int ph = 0; ph < 2; ++ph) {
        if (ph) __syncthreads();   // phase-0 readers done before overwrite
        #pragma unroll
        for (int j2 = 0; j2 < 2; ++j2) {
            const int j = (ph << 1) + j2;
            const int br = (j2 << 4) + col;            // 0..31
            #pragma unroll
            for (int i = 0; i < 4; ++i) {
                const int s = (w << 4) + (i << 2) + kq;
                lds4[(br << 6) + (s ^ br)] = acc[i][j];
            }
        }
        __syncthreads();
        // readback: 8 rows per wave; lane l takes logical slot l of the row
        #pragma unroll
        for (int r = 0; r < 8; ++r) {
            const int br = (w << 3) + r;
            const f32x4 vv = lds4[(br << 6) + (lane ^ br)];
            float* dst = out + (size_t)(b0 + (ph << 5) + br) * PP + P0 + (lane << 2);
            __builtin_nontemporal_store(vv, reinterpret_cast<f32x4*>(dst));
        }
    }
}

extern "C" void kernel_launch(void* const* d_in, const int* in_sizes, int n_in,
                              void* d_out, int out_size, void* d_ws, size_t ws_size,
                              hipStream_t stream) {
    const int*   x = (const int*)d_in[0];
    const float* W = (const float*)d_in[1];
    const float* V = (const float*)d_in[2];
    float* out = (float*)d_out;

    // workspace: Hb_tiled [4096*128] bf16 (1 MB), then Vb_tiled [32000*128] bf16 (8 MB)
    unsigned short* Hb = (unsigned short*)d_ws;
    unsigned short* Vb = Hb + (size_t)BBATCH * DD;

    prep_hidden_kernel<<<BBATCH / 2, 256, 0, stream>>>(x, W, Hb);
    prep_v_kernel<<<(PP * DD) / (8 * 256), 256, 0, stream>>>(V, Vb);
    // 125 p-blocks (256 wide) x 64 b-blocks = 8000 blocks x 4 waves
    gemm_kernel<<<8000, 256, 0, stream>>>(Vb, Hb, out);
}